// Round 3
// baseline (1171.640 us; speedup 1.0000x reference)
//
#include <hip/hip_runtime.h>

#define E_NUM 16
#define DM 2048
#define DH 1408
#define NTOK 32768
#define TMAX 272          // sum_e ceil(c_e/128) <= 256 + 16;  272 = 8*34
#define TILE_U16 8192     // 128 rows x 64 cols bf16 tile image
#define HT_ROWSTRIDE (22 * TILE_U16)   // u16 per 128-token row-tile of H

typedef unsigned short u16;
typedef unsigned int u32;
typedef float f32x4 __attribute__((ext_vector_type(4)));
typedef __bf16 bf16x8 __attribute__((ext_vector_type(8)));
typedef short short8 __attribute__((ext_vector_type(8)));

__device__ __forceinline__ u16 f2bf(float x) {
  u32 u = __builtin_bit_cast(u32, x);
  u = (u + 0x7FFFu + ((u >> 16) & 1u)) >> 16;   // RNE
  return (u16)u;
}
__device__ __forceinline__ u32 f2bf2(float lo, float hi) {
  return (u32)f2bf(lo) | ((u32)f2bf(hi) << 16);
}

// MFMA shim (signature-agnostic), proven in R1/R2.
template <typename V>
__device__ __forceinline__ auto mfma_16x16x32(V a, V b, f32x4 c, int)
    -> decltype(__builtin_amdgcn_mfma_f32_16x16x32_bf16(a, b, c, 0, 0, 0)) {
  return __builtin_amdgcn_mfma_f32_16x16x32_bf16(a, b, c, 0, 0, 0);
}
template <typename V>
__device__ __forceinline__ f32x4 mfma_16x16x32(V a, V b, f32x4 c, long) {
  return __builtin_amdgcn_mfma_f32_16x16x32_bf16(
      __builtin_bit_cast(short8, a), __builtin_bit_cast(short8, b), c, 0, 0, 0);
}
__device__ __forceinline__ f32x4 MFMA(bf16x8 a, bf16x8 b, f32x4 c) {
  return mfma_16x16x32(a, b, c, 0);
}

__device__ __forceinline__ void gll16(const void* g, void* l) {
  __builtin_amdgcn_global_load_lds((const u32*)g, (u32*)l, 16, 0, 0);
}

__device__ __forceinline__ bf16x8 ld_frag(const u16* p) {
  return __builtin_bit_cast(bf16x8, *(const uint4*)p);
}

// ---------------------------------------------------------------------------
// Weight tiler: src f32 [E][K][N] -> dst bf16 tile images
// [E][N/128][K/64][8192], image pos (row, c) holds W[k0+(c^(row&7))*8+j][n0+row]
// ---------------------------------------------------------------------------
__global__ void wtile(const float* __restrict__ src, u16* __restrict__ dst,
                      int K, int N) {
  __shared__ float t[64][133];
  __shared__ u16 img[TILE_U16];
  const int kt = blockIdx.x, nt = blockIdx.y, e = blockIdx.z;
  const int tid = threadIdx.x;
  const size_t sbase = (size_t)e * K * N + (size_t)kt * 64 * N + (size_t)nt * 128;

#pragma unroll
  for (int i = 0; i < 8; i++) {
    int uid = i * 256 + tid;
    int kr = uid >> 5, nc = (uid & 31) * 4;
    float4 v = *(const float4*)&src[sbase + (size_t)kr * N + nc];
    t[kr][nc + 0] = v.x; t[kr][nc + 1] = v.y;
    t[kr][nc + 2] = v.z; t[kr][nc + 3] = v.w;
  }
  __syncthreads();
#pragma unroll
  for (int i = 0; i < 4; i++) {
    int uid = i * 256 + tid;
    int row = uid >> 3, c = uid & 7;
    int kc = (c ^ (row & 7)) * 8;
    uint4 w;
    w.x = f2bf2(t[kc + 0][row], t[kc + 1][row]);
    w.y = f2bf2(t[kc + 2][row], t[kc + 3][row]);
    w.z = f2bf2(t[kc + 4][row], t[kc + 5][row]);
    w.w = f2bf2(t[kc + 6][row], t[kc + 7][row]);
    *(uint4*)&img[uid * 8] = w;
  }
  __syncthreads();
  const size_t dbase = (((size_t)e * (N / 128) + nt) * (K / 64) + kt) * TILE_U16;
#pragma unroll
  for (int i = 0; i < 4; i++) {
    int uid = i * 256 + tid;
    *(uint4*)&dst[dbase + uid * 8] = *(const uint4*)&img[uid * 8];
  }
}

// Map linear row-tile index -> (expert, row0, valid).
__device__ __forceinline__ bool tile_map(const int* __restrict__ cnt, int t,
                                         int& e_out, int& row0, int& valid) {
  int e = -1, ti = 0, seg0 = 0, segc = 0, tacc = 0, off = 0;
#pragma unroll
  for (int i = 0; i < E_NUM; i++) {
    int ci = cnt[i];
    int nt = (ci + 127) >> 7;
    if (e < 0 && t < tacc + nt) { e = i; ti = t - tacc; seg0 = off; segc = ci; }
    tacc += nt; off += ci;
  }
  if (e < 0) return false;
  e_out = e;
  row0 = seg0 + ti * 128;
  int v = seg0 + segc - row0;
  valid = v < 128 ? v : 128;
  return true;
}

// XCD-chunked bijective swizzle: consecutive dispatch ids round-robin XCDs;
// give each XCD a contiguous chunk of 34 tiles (272 = 8*34).
__device__ __forceinline__ int xcd_swz(int bx) {
  return (bx & 7) * (TMAX / 8) + (bx >> 3);
}

// ---------------------------------------------------------------------------
// Fused gate+up grouped GEMM + SwiGLU (2-phase: B double-buffered via gll,
// A single-buffered reg-staged with one-step reg prefetch).
// ---------------------------------------------------------------------------
__global__ __launch_bounds__(256, 2) void gemm_gate_up(
    const float* __restrict__ X, const u16* __restrict__ WgT,
    const u16* __restrict__ WuT, const int* __restrict__ cnt,
    u16* __restrict__ H) {
  __shared__ u16 As[TILE_U16];
  __shared__ u16 Bgs[2][TILE_U16];
  __shared__ u16 Bus[2][TILE_U16];

  int e, row0, valid;
  if (!tile_map(cnt, xcd_swz(blockIdx.x), e, row0, valid)) return;
  const int n0t = blockIdx.y;  // 0..10

  const int tid = threadIdx.x;
  const int lane = tid & 63;
  const int wave = tid >> 6;
  const int wr = (wave >> 1) * 64, wc = (wave & 1) * 64;
  const int l15 = lane & 15, l4 = lane >> 4;

  const float* pA[4];
  u32 aso[4];
#pragma unroll
  for (int q = 0; q < 4; q++) {
    int u = q * 256 + tid;
    int lr = u >> 3, c = u & 7;
    int R = row0 + (lr < valid ? lr : 0);
    pA[q] = X + (size_t)R * DM + c * 8;
    aso[q] = lr * 64 + ((c ^ (R & 7)) * 8);
  }
  const size_t btb = (((size_t)e * 11 + n0t) * 32) * TILE_U16;
  const u16* bgp = WgT + btb;
  const u16* bup = WuT + btb;

  f32x4 accg[4][4], accu[4][4];
#pragma unroll
  for (int i = 0; i < 4; i++)
#pragma unroll
    for (int j = 0; j < 4; j++) {
      accg[i][j] = (f32x4){0.f, 0.f, 0.f, 0.f};
      accu[i][j] = (f32x4){0.f, 0.f, 0.f, 0.f};
    }

  float4 a0[4], a1[4];

  // ---- prologue: stage kt=0 ----
#pragma unroll
  for (int q = 0; q < 4; q++) {
    int u = q * 256 + tid;
    gll16(bgp + u * 8, &Bgs[0][u * 8]);
    gll16(bup + u * 8, &Bus[0][u * 8]);
  }
#pragma unroll
  for (int q = 0; q < 4; q++) {
    a0[q] = *(const float4*)pA[q];
    a1[q] = *(const float4*)(pA[q] + 4);
  }
#pragma unroll
  for (int q = 0; q < 4; q++) {
    uint4 w;
    w.x = f2bf2(a0[q].x, a0[q].y); w.y = f2bf2(a0[q].z, a0[q].w);
    w.z = f2bf2(a1[q].x, a1[q].y); w.w = f2bf2(a1[q].z, a1[q].w);
    *(uint4*)&As[aso[q]] = w;
  }
  __syncthreads();

  int cur = 0;
  for (int kt = 0; kt < 32; kt++) {
    // issue next B-tile loads into the other buffer: in flight under MFMA
    if (kt + 1 < 32) {
      const u16* bgn = bgp + (size_t)(kt + 1) * TILE_U16;
      const u16* bun = bup + (size_t)(kt + 1) * TILE_U16;
#pragma unroll
      for (int q = 0; q < 4; q++) {
        int u = q * 256 + tid;
        gll16(bgn + u * 8, &Bgs[cur ^ 1][u * 8]);
        gll16(bun + u * 8, &Bus[cur ^ 1][u * 8]);
      }
#pragma unroll
      for (int q = 0; q < 4; q++) {
        const float* ap = pA[q] + (kt + 1) * 64;
        a0[q] = *(const float4*)ap;
        a1[q] = *(const float4*)(ap + 4);
      }
    }
    // compute on current buffers
#pragma unroll
    for (int kh = 0; kh < 2; kh++) {
      bf16x8 af[4];
#pragma unroll
      for (int i = 0; i < 4; i++) {
        int lr = wr + i * 16 + l15;
        int sw = ((kh * 4 + l4) ^ ((row0 + lr) & 7)) * 8;
        af[i] = ld_frag(&As[lr * 64 + sw]);
      }
#pragma unroll
      for (int j = 0; j < 4; j++) {
        int br = wc + j * 16 + l15;
        int boff = br * 64 + (((kh * 4 + l4) ^ (br & 7)) * 8);
        bf16x8 bg = ld_frag(&Bgs[cur][boff]);
        bf16x8 bu = ld_frag(&Bus[cur][boff]);
#pragma unroll
        for (int i = 0; i < 4; i++) {
          accg[i][j] = MFMA(af[i], bg, accg[i][j]);
          accu[i][j] = MFMA(af[i], bu, accu[i][j]);
        }
      }
    }
    __syncthreads();  // all waves done reading As/B[cur]; drains in-flight glls
    if (kt + 1 < 32) {
      // write next A tile (regs hold kt+1) into the single A buffer
#pragma unroll
      for (int q = 0; q < 4; q++) {
        uint4 w;
        w.x = f2bf2(a0[q].x, a0[q].y); w.y = f2bf2(a0[q].z, a0[q].w);
        w.z = f2bf2(a1[q].x, a1[q].y); w.w = f2bf2(a1[q].z, a1[q].w);
        *(uint4*)&As[aso[q]] = w;
      }
      __syncthreads();
    }
    cur ^= 1;
  }

  // epilogue: h = silu(gate)*up -> H tiled-swizzled image
#pragma unroll
  for (int j = 0; j < 4; j++) {
    int col = n0t * 128 + wc + j * 16 + l15;
    int kt_h = col >> 6, cc = (col & 63) >> 3, ce = col & 7;
#pragma unroll
    for (int i = 0; i < 4; i++) {
      f32x4 g = accg[i][j], u = accu[i][j];
#pragma unroll
      for (int r = 0; r < 4; r++) {
        int rl = wr + i * 16 + l4 * 4 + r;
        if (rl < valid) {
          int R = row0 + rl;
          float gv = g[r];
          float hv = gv / (1.f + __expf(-gv)) * u[r];
          size_t idx = (size_t)(R >> 7) * HT_ROWSTRIDE + (size_t)kt_h * TILE_U16 +
                       (R & 127) * 64 + ((cc ^ (R & 7)) * 8) + ce;
          H[idx] = f2bf(hv);
        }
      }
    }
  }
}

// ---------------------------------------------------------------------------
// Down grouped GEMM (2-phase: both operands gll'd and double-buffered,
// ONE barrier per K-step).
// ---------------------------------------------------------------------------
__global__ __launch_bounds__(256, 2) void gemm_down(
    const u16* __restrict__ Ht, const u16* __restrict__ WdT,
    const int* __restrict__ cnt, float* __restrict__ Out) {
  __shared__ u16 As[2][TILE_U16];
  __shared__ u16 Bs[2][TILE_U16];

  int e, row0, valid;
  if (!tile_map(cnt, xcd_swz(blockIdx.x), e, row0, valid)) return;
  const int n0t = blockIdx.y;  // 0..15

  const int tid = threadIdx.x;
  const int lane = tid & 63;
  const int wave = tid >> 6;
  const int wr = (wave >> 1) * 64, wc = (wave & 1) * 64;
  const int l15 = lane & 15, l4 = lane >> 4;

  const u16* pA[4];
#pragma unroll
  for (int q = 0; q < 4; q++) {
    int u = q * 256 + tid;
    int lr = u >> 3, c = u & 7;
    int R = row0 + (lr < valid ? lr : 0);
    pA[q] = Ht + (size_t)(R >> 7) * HT_ROWSTRIDE + (size_t)(R & 127) * 64 + c * 8;
  }
  const size_t btb = (((size_t)e * 16 + n0t) * 22) * TILE_U16;
  const u16* bp = WdT + btb;

  f32x4 acc[4][4];
#pragma unroll
  for (int i = 0; i < 4; i++)
#pragma unroll
    for (int j = 0; j < 4; j++) acc[i][j] = (f32x4){0.f, 0.f, 0.f, 0.f};

  // prologue: stage kt=0
#pragma unroll
  for (int q = 0; q < 4; q++) {
    int u = q * 256 + tid;
    gll16(pA[q], &As[0][u * 8]);
    gll16(bp + u * 8, &Bs[0][u * 8]);
  }
  __syncthreads();

  int cur = 0;
  for (int kt = 0; kt < 22; kt++) {
    if (kt + 1 < 22) {
#pragma unroll
      for (int q = 0; q < 4; q++) {
        int u = q * 256 + tid;
        gll16(pA[q] + (size_t)(kt + 1) * TILE_U16, &As[cur ^ 1][u * 8]);
        gll16(bp + (size_t)(kt + 1) * TILE_U16 + u * 8, &Bs[cur ^ 1][u * 8]);
      }
    }
#pragma unroll
    for (int kh = 0; kh < 2; kh++) {
      bf16x8 af[4];
#pragma unroll
      for (int i = 0; i < 4; i++) {
        int lr = wr + i * 16 + l15;
        int sw = ((kh * 4 + l4) ^ ((row0 + lr) & 7)) * 8;
        af[i] = ld_frag(&As[cur][lr * 64 + sw]);
      }
#pragma unroll
      for (int j = 0; j < 4; j++) {
        int br = wc + j * 16 + l15;
        int boff = br * 64 + (((kh * 4 + l4) ^ (br & 7)) * 8);
        bf16x8 bf = ld_frag(&Bs[cur][boff]);
#pragma unroll
        for (int i = 0; i < 4; i++) acc[i][j] = MFMA(af[i], bf, acc[i][j]);
      }
    }
    __syncthreads();  // readers done + everyone's next-tile glls landed
    cur ^= 1;
  }

#pragma unroll
  for (int j = 0; j < 4; j++) {
#pragma unroll
    for (int i = 0; i < 4; i++) {
#pragma unroll
      for (int r = 0; r < 4; r++) {
        int rl = wr + i * 16 + l4 * 4 + r;
        if (rl < valid)
          Out[(size_t)(row0 + rl) * DM + n0t * 128 + wc + j * 16 + l15] =
              acc[i][j][r];
      }
    }
  }
}

extern "C" void kernel_launch(void* const* d_in, const int* in_sizes, int n_in,
                              void* d_out, int out_size, void* d_ws, size_t ws_size,
                              hipStream_t stream) {
  const float* inp = (const float*)d_in[0];
  const float* w_gate = (const float*)d_in[1];
  const float* w_up = (const float*)d_in[2];
  const float* w_down = (const float*)d_in[3];
  const int* cnt = (const int*)d_in[4];
  float* out = (float*)d_out;

  const size_t WELEMS = (size_t)E_NUM * DM * DH;  // 46,137,344 u16 each
  if (ws_size < 3 * WELEMS * sizeof(u16)) return;

  u16* wgT = (u16*)d_ws;      // gate tiles [E][11][32][8192]; later w_down tiles
  u16* wuT = wgT + WELEMS;    // up tiles
  u16* Ht = wuT + WELEMS;     // H tile images [256][22][8192]

  dim3 blk(256);
  wtile<<<dim3(DM / 64, DH / 128, E_NUM), blk, 0, stream>>>(w_gate, wgT, DM, DH);
  wtile<<<dim3(DM / 64, DH / 128, E_NUM), blk, 0, stream>>>(w_up, wuT, DM, DH);
  gemm_gate_up<<<dim3(TMAX, DH / 128), blk, 0, stream>>>(inp, wgT, wuT, cnt, Ht);
  wtile<<<dim3(DH / 64, DM / 128, E_NUM), blk, 0, stream>>>(w_down, wgT, DH, DM);
  gemm_down<<<dim3(TMAX, DM / 128), blk, 0, stream>>>(Ht, wgT, cnt, out);
}

// Round 4
// 1092.826 us; speedup vs baseline: 1.0721x; 1.0721x over previous
//
#include <hip/hip_runtime.h>

#define E_NUM 16
#define DM 2048
#define DH 1408
#define NTOK 32768
#define TMAX 144           // sum_e ceil(c_e/256) <= 128 + 16; 144 = 8*18
#define TILE_U16 8192      // one 128x64 bf16 image
#define XI_RS (32 * TILE_U16)   // u16 per 128-row X image group (32 ktiles)
#define HT_RS (22 * TILE_U16)   // u16 per 128-row H image group (22 ktiles)

typedef unsigned short u16;
typedef unsigned int u32;
typedef float f32x4 __attribute__((ext_vector_type(4)));
typedef __bf16 bf16x8 __attribute__((ext_vector_type(8)));
typedef short short8 __attribute__((ext_vector_type(8)));

__device__ __forceinline__ u16 f2bf(float x) {
  u32 u = __builtin_bit_cast(u32, x);
  u = (u + 0x7FFFu + ((u >> 16) & 1u)) >> 16;   // RNE
  return (u16)u;
}
__device__ __forceinline__ u32 f2bf2(float lo, float hi) {
  return (u32)f2bf(lo) | ((u32)f2bf(hi) << 16);
}

template <typename V>
__device__ __forceinline__ auto mfma_16x16x32(V a, V b, f32x4 c, int)
    -> decltype(__builtin_amdgcn_mfma_f32_16x16x32_bf16(a, b, c, 0, 0, 0)) {
  return __builtin_amdgcn_mfma_f32_16x16x32_bf16(a, b, c, 0, 0, 0);
}
template <typename V>
__device__ __forceinline__ f32x4 mfma_16x16x32(V a, V b, f32x4 c, long) {
  return __builtin_amdgcn_mfma_f32_16x16x32_bf16(
      __builtin_bit_cast(short8, a), __builtin_bit_cast(short8, b), c, 0, 0, 0);
}
__device__ __forceinline__ f32x4 MFMA(bf16x8 a, bf16x8 b, f32x4 c) {
  return mfma_16x16x32(a, b, c, 0);
}

__device__ __forceinline__ void gll16(const void* g, void* l) {
  __builtin_amdgcn_global_load_lds((const u32*)g, (u32*)l, 16, 0, 0);
}
__device__ __forceinline__ bf16x8 ld_frag(const u16* p) {
  return __builtin_bit_cast(bf16x8, *(const uint4*)p);
}

// ---------------------------------------------------------------------------
// X tiler: f32 [NTOK][DM] -> bf16 images [256][32][8192], phys chunk = c^(row&7)
// ---------------------------------------------------------------------------
__global__ void xtile(const float* __restrict__ src, u16* __restrict__ dst) {
  const int kt = blockIdx.x;   // 0..31
  const int rt = blockIdx.y;   // 0..255
  const int tid = threadIdx.x;
  const float* s = src + (size_t)rt * 128 * DM + kt * 64;
  u16* d = dst + (size_t)rt * XI_RS + (size_t)kt * TILE_U16;
#pragma unroll
  for (int i = 0; i < 4; ++i) {
    int u = i * 256 + tid;
    int row = u >> 3, c = u & 7;
    const float* p = s + (size_t)row * DM + c * 8;
    float4 v0 = *(const float4*)p, v1 = *(const float4*)(p + 4);
    uint4 w;
    w.x = f2bf2(v0.x, v0.y); w.y = f2bf2(v0.z, v0.w);
    w.z = f2bf2(v1.x, v1.y); w.w = f2bf2(v1.z, v1.w);
    *(uint4*)&d[(size_t)row * 64 + ((c ^ (row & 7)) * 8)] = w;
  }
}

// ---------------------------------------------------------------------------
// Weight tiler (unchanged from R2/R3): f32 [E][K][N] -> bf16 images
// [E][N/128][K/64][8192], phys chunk = c^(row&7), row = output col
// ---------------------------------------------------------------------------
__global__ void wtile(const float* __restrict__ src, u16* __restrict__ dst,
                      int K, int N) {
  __shared__ float t[64][133];
  __shared__ u16 img[TILE_U16];
  const int kt = blockIdx.x, nt = blockIdx.y, e = blockIdx.z;
  const int tid = threadIdx.x;
  const size_t sbase = (size_t)e * K * N + (size_t)kt * 64 * N + (size_t)nt * 128;

#pragma unroll
  for (int i = 0; i < 8; i++) {
    int uid = i * 256 + tid;
    int kr = uid >> 5, nc = (uid & 31) * 4;
    float4 v = *(const float4*)&src[sbase + (size_t)kr * N + nc];
    t[kr][nc + 0] = v.x; t[kr][nc + 1] = v.y;
    t[kr][nc + 2] = v.z; t[kr][nc + 3] = v.w;
  }
  __syncthreads();
#pragma unroll
  for (int i = 0; i < 4; i++) {
    int uid = i * 256 + tid;
    int row = uid >> 3, c = uid & 7;
    int kc = (c ^ (row & 7)) * 8;
    uint4 w;
    w.x = f2bf2(t[kc + 0][row], t[kc + 1][row]);
    w.y = f2bf2(t[kc + 2][row], t[kc + 3][row]);
    w.z = f2bf2(t[kc + 4][row], t[kc + 5][row]);
    w.w = f2bf2(t[kc + 6][row], t[kc + 7][row]);
    *(uint4*)&img[uid * 8] = w;
  }
  __syncthreads();
  const size_t dbase = (((size_t)e * (N / 128) + nt) * (K / 64) + kt) * TILE_U16;
#pragma unroll
  for (int i = 0; i < 4; i++) {
    int uid = i * 256 + tid;
    *(uint4*)&dst[dbase + uid * 8] = *(const uint4*)&img[uid * 8];
  }
}

// Map linear 256-row tile index -> (expert, row0, valid).
__device__ __forceinline__ bool tile_map(const int* __restrict__ cnt, int t,
                                         int& e_out, int& row0, int& valid) {
  int e = -1, ti = 0, seg0 = 0, segc = 0, tacc = 0, off = 0;
#pragma unroll
  for (int i = 0; i < E_NUM; i++) {
    int ci = cnt[i];
    int nt = (ci + 255) >> 8;
    if (e < 0 && t < tacc + nt) { e = i; ti = t - tacc; seg0 = off; segc = ci; }
    tacc += nt; off += ci;
  }
  if (e < 0) return false;
  e_out = e;
  row0 = seg0 + ti * 256;
  int v = seg0 + segc - row0;
  valid = v < 256 ? v : 256;
  return true;
}

__device__ __forceinline__ int xcd_swz(int bx) {
  return (bx & 7) * (TMAX / 8) + (bx >> 3);
}

// ---------------------------------------------------------------------------
// Fused gate+up grouped GEMM + SwiGLU. BM=256, BN=128, 512 thr, 2-buffer,
// 1 raw barrier + vmcnt drain-after-cover per K-tile, pure-gll staging.
// ---------------------------------------------------------------------------
__global__ __launch_bounds__(512, 2) void gemm_gate_up(
    const u16* __restrict__ Xi, const u16* __restrict__ WgT,
    const u16* __restrict__ WuT, const int* __restrict__ cnt,
    u16* __restrict__ H) {
  __shared__ u16 As[2][2 * TILE_U16];   // 256x64 bf16 (two stacked images)
  __shared__ u16 Bgs[2][TILE_U16];
  __shared__ u16 Bus[2][TILE_U16];

  int e, row0, valid;
  if (!tile_map(cnt, xcd_swz(blockIdx.x), e, row0, valid)) return;
  const int n0t = blockIdx.y;  // 0..10

  const int tid = threadIdx.x;
  const int lane = tid & 63;
  const int wave = tid >> 6;                 // 0..7
  const int wr = (wave >> 1) * 64;           // row offset (4 groups)
  const int wcn = (wave & 1) * 64;           // col offset (2 groups)
  const int l15 = lane & 15, l4 = lane >> 4;
  const int swz = l15 & 7;

  // A staging sources: unit u = q*512+tid -> lds row lr=u>>3, phys chunk cs=u&7
  const u16* pA[4];
#pragma unroll
  for (int q = 0; q < 4; ++q) {
    int u = q * 512 + tid;
    int lr = u >> 3, cs = u & 7;
    int R = row0 + (lr < valid ? lr : 0);
    int srcc = cs ^ (lr & 7) ^ (R & 7);      // image phys chunk holding logical cs^(lr&7)
    pA[q] = Xi + (size_t)(R >> 7) * XI_RS + (size_t)(R & 127) * 64 + srcc * 8;
  }
  const size_t btb = (((size_t)e * 11 + n0t) * 32) * TILE_U16;
  const u16* pBg[2];
  const u16* pBu[2];
#pragma unroll
  for (int q = 0; q < 2; ++q) {
    int ub = q * 512 + tid;
    pBg[q] = WgT + btb + ub * 8;
    pBu[q] = WuT + btb + ub * 8;
  }

  f32x4 accg[4][4], accu[4][4];
#pragma unroll
  for (int i = 0; i < 4; i++)
#pragma unroll
    for (int j = 0; j < 4; j++) {
      accg[i][j] = (f32x4){0.f, 0.f, 0.f, 0.f};
      accu[i][j] = (f32x4){0.f, 0.f, 0.f, 0.f};
    }

  // prologue: empty the vm queue, then stage tile 0
  asm volatile("s_waitcnt vmcnt(0)" ::: "memory");
#pragma unroll
  for (int q = 0; q < 4; ++q) gll16(pA[q], &As[0][(q * 512 + tid) * 8]);
#pragma unroll
  for (int q = 0; q < 2; ++q) {
    gll16(pBg[q], &Bgs[0][(q * 512 + tid) * 8]);
    gll16(pBu[q], &Bus[0][(q * 512 + tid) * 8]);
  }

  for (int kt = 0; kt < 32; ++kt) {
    // own tile-kt loads landed (they had the previous compute phase to fly)
    asm volatile("s_waitcnt vmcnt(0)" ::: "memory");
    __builtin_amdgcn_s_barrier();            // everyone's landed -> tile complete
    __builtin_amdgcn_sched_barrier(0);

    if (kt + 1 < 32) {                       // stage kt+1 into the other buffer
      const int nb = (kt + 1) & 1;
      const size_t ko = (size_t)(kt + 1) * TILE_U16;
#pragma unroll
      for (int q = 0; q < 4; ++q)
        gll16(pA[q] + ko, &As[nb][(q * 512 + tid) * 8]);
#pragma unroll
      for (int q = 0; q < 2; ++q) {
        gll16(pBg[q] + ko, &Bgs[nb][(q * 512 + tid) * 8]);
        gll16(pBu[q] + ko, &Bus[nb][(q * 512 + tid) * 8]);
      }
    }

    const u16* cA = &As[kt & 1][0];
    const u16* cBg = &Bgs[kt & 1][0];
    const u16* cBu = &Bus[kt & 1][0];
#pragma unroll
    for (int kh = 0; kh < 2; ++kh) {
      const int co = ((kh * 4 + l4) ^ swz) * 8;
      bf16x8 af[4], bg[4], bu[4];
#pragma unroll
      for (int i = 0; i < 4; ++i)
        af[i] = ld_frag(cA + (wr + i * 16 + l15) * 64 + co);
#pragma unroll
      for (int j = 0; j < 4; ++j) {
        bg[j] = ld_frag(cBg + (wcn + j * 16 + l15) * 64 + co);
        bu[j] = ld_frag(cBu + (wcn + j * 16 + l15) * 64 + co);
      }
      __builtin_amdgcn_s_setprio(1);
#pragma unroll
      for (int j = 0; j < 4; ++j)
#pragma unroll
        for (int i = 0; i < 4; ++i) {
          accg[i][j] = MFMA(af[i], bg[j], accg[i][j]);
          accu[i][j] = MFMA(af[i], bu[j], accu[i][j]);
        }
      __builtin_amdgcn_s_setprio(0);
    }
  }

  // epilogue: h = silu(gate)*up -> H swizzled images
#pragma unroll
  for (int j = 0; j < 4; ++j) {
    int col = n0t * 128 + wcn + j * 16 + l15;
    int kt_h = col >> 6, cc = (col & 63) >> 3, ce = col & 7;
#pragma unroll
    for (int i = 0; i < 4; ++i) {
      f32x4 g = accg[i][j], u = accu[i][j];
#pragma unroll
      for (int r = 0; r < 4; ++r) {
        int rl = wr + i * 16 + l4 * 4 + r;
        if (rl < valid) {
          int R = row0 + rl;
          float gv = g[r];
          float hv = gv / (1.f + __expf(-gv)) * u[r];
          size_t idx = (size_t)(R >> 7) * HT_RS + (size_t)kt_h * TILE_U16 +
                       (size_t)(R & 127) * 64 + ((cc ^ (R & 7)) * 8) + ce;
          H[idx] = f2bf(hv);
        }
      }
    }
  }
}

// ---------------------------------------------------------------------------
// Down grouped GEMM. BM=256, BN=128, 512 thr, 3-slot ring, counted vmcnt(6),
// 1 raw barrier per K-tile, 2-tiles-ahead staging.
// ---------------------------------------------------------------------------
__global__ __launch_bounds__(512, 2) void gemm_down(
    const u16* __restrict__ Ht, const u16* __restrict__ WdT,
    const int* __restrict__ cnt, float* __restrict__ Out) {
  __shared__ u16 As[3][2 * TILE_U16];
  __shared__ u16 Bs[3][TILE_U16];

  int e, row0, valid;
  if (!tile_map(cnt, xcd_swz(blockIdx.x), e, row0, valid)) return;
  const int n0t = blockIdx.y;  // 0..15

  const int tid = threadIdx.x;
  const int lane = tid & 63;
  const int wave = tid >> 6;
  const int wr = (wave >> 1) * 64, wcn = (wave & 1) * 64;
  const int l15 = lane & 15, l4 = lane >> 4;
  const int swz = l15 & 7;

  const u16* pA[4];
#pragma unroll
  for (int q = 0; q < 4; ++q) {
    int u = q * 512 + tid;
    int lr = u >> 3, cs = u & 7;
    int R = row0 + (lr < valid ? lr : 0);
    int srcc = cs ^ (lr & 7) ^ (R & 7);
    pA[q] = Ht + (size_t)(R >> 7) * HT_RS + (size_t)(R & 127) * 64 + srcc * 8;
  }
  const size_t btb = (((size_t)e * 16 + n0t) * 22) * TILE_U16;
  const u16* pB[2];
#pragma unroll
  for (int q = 0; q < 2; ++q) pB[q] = WdT + btb + (q * 512 + tid) * 8;

  f32x4 acc[4][4];
#pragma unroll
  for (int i = 0; i < 4; i++)
#pragma unroll
    for (int j = 0; j < 4; j++) acc[i][j] = (f32x4){0.f, 0.f, 0.f, 0.f};

  // prologue: stage tiles 0 and 1
  asm volatile("s_waitcnt vmcnt(0)" ::: "memory");
#pragma unroll
  for (int t0 = 0; t0 < 2; ++t0) {
    const size_t ko = (size_t)t0 * TILE_U16;
#pragma unroll
    for (int q = 0; q < 4; ++q) gll16(pA[q] + ko, &As[t0][(q * 512 + tid) * 8]);
#pragma unroll
    for (int q = 0; q < 2; ++q) gll16(pB[q] + ko, &Bs[t0][(q * 512 + tid) * 8]);
  }

  int cur = 0;
  for (int kt = 0; kt < 22; ++kt) {
    if (kt == 21) {
      asm volatile("s_waitcnt vmcnt(0)" ::: "memory");
    } else {
      asm volatile("s_waitcnt vmcnt(6)" ::: "memory");   // keep next tile's 6 in flight
    }
    __builtin_amdgcn_s_barrier();
    __builtin_amdgcn_sched_barrier(0);

    if (kt + 2 < 22) {                       // stage kt+2 into slot (cur+2)%3
      int sw = cur + 2; if (sw >= 3) sw -= 3;
      const size_t ko = (size_t)(kt + 2) * TILE_U16;
#pragma unroll
      for (int q = 0; q < 4; ++q)
        gll16(pA[q] + ko, &As[sw][(q * 512 + tid) * 8]);
#pragma unroll
      for (int q = 0; q < 2; ++q)
        gll16(pB[q] + ko, &Bs[sw][(q * 512 + tid) * 8]);
    }

    const u16* cA = &As[cur][0];
    const u16* cB = &Bs[cur][0];
#pragma unroll
    for (int kh = 0; kh < 2; ++kh) {
      const int co = ((kh * 4 + l4) ^ swz) * 8;
      bf16x8 af[4], bf[4];
#pragma unroll
      for (int i = 0; i < 4; ++i)
        af[i] = ld_frag(cA + (wr + i * 16 + l15) * 64 + co);
#pragma unroll
      for (int j = 0; j < 4; ++j)
        bf[j] = ld_frag(cB + (wcn + j * 16 + l15) * 64 + co);
      __builtin_amdgcn_s_setprio(1);
#pragma unroll
      for (int j = 0; j < 4; ++j)
#pragma unroll
        for (int i = 0; i < 4; ++i) acc[i][j] = MFMA(af[i], bf[j], acc[i][j]);
      __builtin_amdgcn_s_setprio(0);
    }
    cur += 1; if (cur >= 3) cur = 0;
  }

#pragma unroll
  for (int j = 0; j < 4; ++j) {
#pragma unroll
    for (int i = 0; i < 4; ++i) {
#pragma unroll
      for (int r = 0; r < 4; ++r) {
        int rl = wr + i * 16 + l4 * 4 + r;
        if (rl < valid)
          Out[(size_t)(row0 + rl) * DM + n0t * 128 + wcn + j * 16 + l15] =
              acc[i][j][r];
      }
    }
  }
}

extern "C" void kernel_launch(void* const* d_in, const int* in_sizes, int n_in,
                              void* d_out, int out_size, void* d_ws, size_t ws_size,
                              hipStream_t stream) {
  const float* inp = (const float*)d_in[0];
  const float* w_gate = (const float*)d_in[1];
  const float* w_up = (const float*)d_in[2];
  const float* w_down = (const float*)d_in[3];
  const int* cnt = (const int*)d_in[4];
  float* out = (float*)d_out;

  const size_t XI_ELEMS = (size_t)NTOK * DM;       // 67,108,864 u16 (128 MiB)
  const size_t WELEMS = (size_t)E_NUM * DM * DH;   // 46,137,344 u16 (88 MiB)
  if (ws_size < (XI_ELEMS + 3 * WELEMS) * sizeof(u16)) return;  // 411 MB

  u16* Xi = (u16*)d_ws;        // X images [256][32][8192]
  u16* wgT = Xi + XI_ELEMS;    // gate tiles [E][11][32][8192]; later w_down
  u16* wuT = wgT + WELEMS;     // up tiles
  u16* Ht = wuT + WELEMS;      // H images [256][22][8192]

  xtile<<<dim3(32, 256), 256, 0, stream>>>(inp, Xi);
  wtile<<<dim3(DM / 64, DH / 128, E_NUM), 256, 0, stream>>>(w_gate, wgT, DM, DH);
  wtile<<<dim3(DM / 64, DH / 128, E_NUM), 256, 0, stream>>>(w_up, wuT, DM, DH);
  gemm_gate_up<<<dim3(TMAX, DH / 128), 512, 0, stream>>>(Xi, wgT, wuT, cnt, Ht);
  // wgT region dead now; reuse for w_down tiles [E][16][22][8192]
  wtile<<<dim3(DH / 64, DM / 128, E_NUM), 256, 0, stream>>>(w_down, wgT, DH, DM);
  gemm_down<<<dim3(TMAX, DM / 128), 512, 0, stream>>>(Ht, wgT, cnt, out);
}

// Round 5
// 1064.827 us; speedup vs baseline: 1.1003x; 1.0263x over previous
//
#include <hip/hip_runtime.h>

#define E_NUM 16
#define DM 2048
#define DH 1408
#define NTOK 32768
#define TMAX 144           // sum_e ceil(c_e/256) <= 128 + 16; 144 = 8*18
#define TILE_U16 8192      // one 128x64 bf16 image
#define XI_RS (32 * TILE_U16)   // u16 per 128-row X image group (32 ktiles)
#define HT_RS (22 * TILE_U16)   // u16 per 128-row H image group (22 ktiles)

typedef unsigned short u16;
typedef unsigned int u32;
typedef float f32x4 __attribute__((ext_vector_type(4)));
typedef __bf16 bf16x8 __attribute__((ext_vector_type(8)));
typedef short short8 __attribute__((ext_vector_type(8)));

__device__ __forceinline__ u16 f2bf(float x) {
  u32 u = __builtin_bit_cast(u32, x);
  u = (u + 0x7FFFu + ((u >> 16) & 1u)) >> 16;   // RNE
  return (u16)u;
}
__device__ __forceinline__ u32 f2bf2(float lo, float hi) {
  return (u32)f2bf(lo) | ((u32)f2bf(hi) << 16);
}

template <typename V>
__device__ __forceinline__ auto mfma_16x16x32(V a, V b, f32x4 c, int)
    -> decltype(__builtin_amdgcn_mfma_f32_16x16x32_bf16(a, b, c, 0, 0, 0)) {
  return __builtin_amdgcn_mfma_f32_16x16x32_bf16(a, b, c, 0, 0, 0);
}
template <typename V>
__device__ __forceinline__ f32x4 mfma_16x16x32(V a, V b, f32x4 c, long) {
  return __builtin_amdgcn_mfma_f32_16x16x32_bf16(
      __builtin_bit_cast(short8, a), __builtin_bit_cast(short8, b), c, 0, 0, 0);
}
__device__ __forceinline__ f32x4 MFMA(bf16x8 a, bf16x8 b, f32x4 c) {
  return mfma_16x16x32(a, b, c, 0);
}

__device__ __forceinline__ void gll16(const void* g, void* l) {
  __builtin_amdgcn_global_load_lds((const u32*)g, (u32*)l, 16, 0, 0);
}
__device__ __forceinline__ bf16x8 ld_frag(const u16* p) {
  return __builtin_bit_cast(bf16x8, *(const uint4*)p);
}
#define SB() __builtin_amdgcn_sched_barrier(0)
#define BAR() __builtin_amdgcn_s_barrier()

// ---------------------------------------------------------------------------
// X tiler: f32 [NTOK][DM] -> bf16 images [256][32][8192], phys chunk = c^(row&7)
// ---------------------------------------------------------------------------
__global__ void xtile(const float* __restrict__ src, u16* __restrict__ dst) {
  const int kt = blockIdx.x;   // 0..31
  const int rt = blockIdx.y;   // 0..255
  const int tid = threadIdx.x;
  const float* s = src + (size_t)rt * 128 * DM + kt * 64;
  u16* d = dst + (size_t)rt * XI_RS + (size_t)kt * TILE_U16;
#pragma unroll
  for (int i = 0; i < 4; ++i) {
    int u = i * 256 + tid;
    int row = u >> 3, c = u & 7;
    const float* p = s + (size_t)row * DM + c * 8;
    float4 v0 = *(const float4*)p, v1 = *(const float4*)(p + 4);
    uint4 w;
    w.x = f2bf2(v0.x, v0.y); w.y = f2bf2(v0.z, v0.w);
    w.z = f2bf2(v1.x, v1.y); w.w = f2bf2(v1.z, v1.w);
    *(uint4*)&d[(size_t)row * 64 + ((c ^ (row & 7)) * 8)] = w;
  }
}

// ---------------------------------------------------------------------------
// Weight tiler: f32 [E][K][N] -> bf16 images [E][N/128][K/64][8192]
// ---------------------------------------------------------------------------
__global__ void wtile(const float* __restrict__ src, u16* __restrict__ dst,
                      int K, int N) {
  __shared__ float t[64][133];
  __shared__ u16 img[TILE_U16];
  const int kt = blockIdx.x, nt = blockIdx.y, e = blockIdx.z;
  const int tid = threadIdx.x;
  const size_t sbase = (size_t)e * K * N + (size_t)kt * 64 * N + (size_t)nt * 128;

#pragma unroll
  for (int i = 0; i < 8; i++) {
    int uid = i * 256 + tid;
    int kr = uid >> 5, nc = (uid & 31) * 4;
    float4 v = *(const float4*)&src[sbase + (size_t)kr * N + nc];
    t[kr][nc + 0] = v.x; t[kr][nc + 1] = v.y;
    t[kr][nc + 2] = v.z; t[kr][nc + 3] = v.w;
  }
  __syncthreads();
#pragma unroll
  for (int i = 0; i < 4; i++) {
    int uid = i * 256 + tid;
    int row = uid >> 3, c = uid & 7;
    int kc = (c ^ (row & 7)) * 8;
    uint4 w;
    w.x = f2bf2(t[kc + 0][row], t[kc + 1][row]);
    w.y = f2bf2(t[kc + 2][row], t[kc + 3][row]);
    w.z = f2bf2(t[kc + 4][row], t[kc + 5][row]);
    w.w = f2bf2(t[kc + 6][row], t[kc + 7][row]);
    *(uint4*)&img[uid * 8] = w;
  }
  __syncthreads();
  const size_t dbase = (((size_t)e * (N / 128) + nt) * (K / 64) + kt) * TILE_U16;
#pragma unroll
  for (int i = 0; i < 4; i++) {
    int uid = i * 256 + tid;
    *(uint4*)&dst[dbase + uid * 8] = *(const uint4*)&img[uid * 8];
  }
}

// Map linear 256-row tile index -> (expert, row0, valid).
__device__ __forceinline__ bool tile_map(const int* __restrict__ cnt, int t,
                                         int& e_out, int& row0, int& valid) {
  int e = -1, ti = 0, seg0 = 0, segc = 0, tacc = 0, off = 0;
#pragma unroll
  for (int i = 0; i < E_NUM; i++) {
    int ci = cnt[i];
    int nt = (ci + 255) >> 8;
    if (e < 0 && t < tacc + nt) { e = i; ti = t - tacc; seg0 = off; segc = ci; }
    tacc += nt; off += ci;
  }
  if (e < 0) return false;
  e_out = e;
  row0 = seg0 + ti * 256;
  int v = seg0 + segc - row0;
  valid = v < 256 ? v : 256;
  return true;
}

__device__ __forceinline__ int xcd_swz(int bx) {
  return (bx & 7) * (TMAX / 8) + (bx >> 3);
}

// ---------------------------------------------------------------------------
// Fused gate+up grouped GEMM + SwiGLU. BM=256, BN=128, 512 thr, 8 waves.
// 4 phases/K-tile, counted vmcnt: A 2-deep (stage kt+1 @p0), B 3-deep ring
// (stage kt+2 @p1), end-of-tile wait vmcnt(4). LDS = 160 KiB exactly.
// ---------------------------------------------------------------------------
__global__ __launch_bounds__(512, 2) void gemm_gate_up(
    const u16* __restrict__ Xi, const u16* __restrict__ WgT,
    const u16* __restrict__ WuT, const int* __restrict__ cnt,
    u16* __restrict__ H) {
  __shared__ u16 As[2][2 * TILE_U16];   // 64 KiB
  __shared__ u16 Bgs[3][TILE_U16];      // 48 KiB
  __shared__ u16 Bus[3][TILE_U16];      // 48 KiB

  int e, row0, valid;
  if (!tile_map(cnt, xcd_swz(blockIdx.x), e, row0, valid)) return;
  const int n0t = blockIdx.y;  // 0..10

  const int tid = threadIdx.x;
  const int lane = tid & 63;
  const int wave = tid >> 6;
  const int wr = (wave >> 1) * 64, wcn = (wave & 1) * 64;
  const int l15 = lane & 15, l4 = lane >> 4;
  const int swz = l15 & 7;

  const u16* pA[4];
#pragma unroll
  for (int q = 0; q < 4; ++q) {
    int u = q * 512 + tid;
    int lr = u >> 3, cs = u & 7;
    int R = row0 + (lr < valid ? lr : 0);
    int srcc = cs ^ (lr & 7) ^ (R & 7);
    pA[q] = Xi + (size_t)(R >> 7) * XI_RS + (size_t)(R & 127) * 64 + srcc * 8;
  }
  const size_t btb = (((size_t)e * 11 + n0t) * 32) * TILE_U16;
  const u16* pBg[2];
  const u16* pBu[2];
#pragma unroll
  for (int q = 0; q < 2; ++q) {
    pBg[q] = WgT + btb + (q * 512 + tid) * 8;
    pBu[q] = WuT + btb + (q * 512 + tid) * 8;
  }

  f32x4 accg[4][4], accu[4][4];
#pragma unroll
  for (int i = 0; i < 4; i++)
#pragma unroll
    for (int j = 0; j < 4; j++) {
      accg[i][j] = (f32x4){0.f, 0.f, 0.f, 0.f};
      accu[i][j] = (f32x4){0.f, 0.f, 0.f, 0.f};
    }

  // prologue: B(0), A(0), B(1); wait leaving B(1)'s 4 in flight
  asm volatile("s_waitcnt vmcnt(0)" ::: "memory");
#pragma unroll
  for (int q = 0; q < 2; ++q) {
    gll16(pBg[q], &Bgs[0][(q * 512 + tid) * 8]);
    gll16(pBu[q], &Bus[0][(q * 512 + tid) * 8]);
  }
#pragma unroll
  for (int q = 0; q < 4; ++q) gll16(pA[q], &As[0][(q * 512 + tid) * 8]);
#pragma unroll
  for (int q = 0; q < 2; ++q) {
    gll16(pBg[q] + TILE_U16, &Bgs[1][(q * 512 + tid) * 8]);
    gll16(pBu[q] + TILE_U16, &Bus[1][(q * 512 + tid) * 8]);
  }
  asm volatile("s_waitcnt vmcnt(4)" ::: "memory");
  SB();
  BAR();

  for (int kt = 0; kt < 32; ++kt) {
    const u16* cA = &As[kt & 1][0];
    const int bs = kt % 3;
    const u16* cBg = &Bgs[bs][0];
    const u16* cBu = &Bus[bs][0];
    bf16x8 af[4];

#pragma unroll
    for (int p = 0; p < 4; ++p) {
      const int kh = p >> 1;
      const int co = ((kh * 4 + l4) ^ swz) * 8;
      // --- phase reads ---
      if ((p & 1) == 0) {
#pragma unroll
        for (int i = 0; i < 4; ++i)
          af[i] = ld_frag(cA + (wr + i * 16 + l15) * 64 + co);
      }
      bf16x8 bgv[2], buv[2];
#pragma unroll
      for (int jj = 0; jj < 2; ++jj) {
        int j = (p & 1) * 2 + jj;
        bgv[jj] = ld_frag(cBg + (wcn + j * 16 + l15) * 64 + co);
        buv[jj] = ld_frag(cBu + (wcn + j * 16 + l15) * 64 + co);
      }
      // --- phase staging ---
      if (p == 0 && kt + 1 < 32) {
        const size_t ko = (size_t)(kt + 1) * TILE_U16;
        const int nb = (kt + 1) & 1;
#pragma unroll
        for (int q = 0; q < 4; ++q) gll16(pA[q] + ko, &As[nb][(q * 512 + tid) * 8]);
      }
      if (p == 1 && kt + 2 < 32) {
        const size_t ko = (size_t)(kt + 2) * TILE_U16;
        const int nb = (kt + 2) % 3;
#pragma unroll
        for (int q = 0; q < 2; ++q) {
          gll16(pBg[q] + ko, &Bgs[nb][(q * 512 + tid) * 8]);
          gll16(pBu[q] + ko, &Bus[nb][(q * 512 + tid) * 8]);
        }
      }
      SB();
      BAR();
      SB();
      __builtin_amdgcn_s_setprio(1);
#pragma unroll
      for (int jj = 0; jj < 2; ++jj) {
        int j = (p & 1) * 2 + jj;
#pragma unroll
        for (int i = 0; i < 4; ++i) {
          accg[i][j] = MFMA(af[i], bgv[jj], accg[i][j]);
          accu[i][j] = MFMA(af[i], buv[jj], accu[i][j]);
        }
      }
      __builtin_amdgcn_s_setprio(0);
      SB();
      if (p < 3) BAR();
    }
    // --- end of K-tile: counted wait, tile-boundary barrier ---
    if (kt + 2 < 32) {
      asm volatile("s_waitcnt vmcnt(4)" ::: "memory");
    } else {
      asm volatile("s_waitcnt vmcnt(0)" ::: "memory");
    }
    SB();
    BAR();
  }

  // epilogue: h = silu(gate)*up -> H swizzled images
#pragma unroll
  for (int j = 0; j < 4; ++j) {
    int col = n0t * 128 + wcn + j * 16 + l15;
    int kt_h = col >> 6, cc = (col & 63) >> 3, ce = col & 7;
#pragma unroll
    for (int i = 0; i < 4; ++i) {
      f32x4 g = accg[i][j], u = accu[i][j];
#pragma unroll
      for (int r = 0; r < 4; ++r) {
        int rl = wr + i * 16 + l4 * 4 + r;
        if (rl < valid) {
          int R = row0 + rl;
          float gv = g[r];
          float hv = gv / (1.f + __expf(-gv)) * u[r];
          size_t idx = (size_t)(R >> 7) * HT_RS + (size_t)kt_h * TILE_U16 +
                       (size_t)(R & 127) * 64 + ((cc ^ (R & 7)) * 8) + ce;
          H[idx] = f2bf(hv);
        }
      }
    }
  }
}

// ---------------------------------------------------------------------------
// Down grouped GEMM. Same 4-phase schedule; A 2-deep, B 3-deep, vmcnt(2).
// LDS = 112 KiB.
// ---------------------------------------------------------------------------
__global__ __launch_bounds__(512, 2) void gemm_down(
    const u16* __restrict__ Ht, const u16* __restrict__ WdT,
    const int* __restrict__ cnt, float* __restrict__ Out) {
  __shared__ u16 As[2][2 * TILE_U16];   // 64 KiB
  __shared__ u16 Bs[3][TILE_U16];       // 48 KiB

  int e, row0, valid;
  if (!tile_map(cnt, xcd_swz(blockIdx.x), e, row0, valid)) return;
  const int n0t = blockIdx.y;  // 0..15

  const int tid = threadIdx.x;
  const int lane = tid & 63;
  const int wave = tid >> 6;
  const int wr = (wave >> 1) * 64, wcn = (wave & 1) * 64;
  const int l15 = lane & 15, l4 = lane >> 4;
  const int swz = l15 & 7;

  const u16* pA[4];
#pragma unroll
  for (int q = 0; q < 4; ++q) {
    int u = q * 512 + tid;
    int lr = u >> 3, cs = u & 7;
    int R = row0 + (lr < valid ? lr : 0);
    int srcc = cs ^ (lr & 7) ^ (R & 7);
    pA[q] = Ht + (size_t)(R >> 7) * HT_RS + (size_t)(R & 127) * 64 + srcc * 8;
  }
  const size_t btb = (((size_t)e * 16 + n0t) * 22) * TILE_U16;
  const u16* pB[2];
#pragma unroll
  for (int q = 0; q < 2; ++q) pB[q] = WdT + btb + (q * 512 + tid) * 8;

  f32x4 acc[4][4];
#pragma unroll
  for (int i = 0; i < 4; i++)
#pragma unroll
    for (int j = 0; j < 4; j++) acc[i][j] = (f32x4){0.f, 0.f, 0.f, 0.f};

  asm volatile("s_waitcnt vmcnt(0)" ::: "memory");
#pragma unroll
  for (int q = 0; q < 2; ++q) gll16(pB[q], &Bs[0][(q * 512 + tid) * 8]);
#pragma unroll
  for (int q = 0; q < 4; ++q) gll16(pA[q], &As[0][(q * 512 + tid) * 8]);
#pragma unroll
  for (int q = 0; q < 2; ++q) gll16(pB[q] + TILE_U16, &Bs[1][(q * 512 + tid) * 8]);
  asm volatile("s_waitcnt vmcnt(2)" ::: "memory");
  SB();
  BAR();

  for (int kt = 0; kt < 22; ++kt) {
    const u16* cA = &As[kt & 1][0];
    const u16* cB = &Bs[kt % 3][0];
    bf16x8 af[4];

#pragma unroll
    for (int p = 0; p < 4; ++p) {
      const int kh = p >> 1;
      const int co = ((kh * 4 + l4) ^ swz) * 8;
      if ((p & 1) == 0) {
#pragma unroll
        for (int i = 0; i < 4; ++i)
          af[i] = ld_frag(cA + (wr + i * 16 + l15) * 64 + co);
      }
      bf16x8 bv[2];
#pragma unroll
      for (int jj = 0; jj < 2; ++jj) {
        int j = (p & 1) * 2 + jj;
        bv[jj] = ld_frag(cB + (wcn + j * 16 + l15) * 64 + co);
      }
      if (p == 0 && kt + 1 < 22) {
        const size_t ko = (size_t)(kt + 1) * TILE_U16;
        const int nb = (kt + 1) & 1;
#pragma unroll
        for (int q = 0; q < 4; ++q) gll16(pA[q] + ko, &As[nb][(q * 512 + tid) * 8]);
      }
      if (p == 1 && kt + 2 < 22) {
        const size_t ko = (size_t)(kt + 2) * TILE_U16;
        const int nb = (kt + 2) % 3;
#pragma unroll
        for (int q = 0; q < 2; ++q) gll16(pB[q] + ko, &Bs[nb][(q * 512 + tid) * 8]);
      }
      SB();
      BAR();
      SB();
      __builtin_amdgcn_s_setprio(1);
#pragma unroll
      for (int jj = 0; jj < 2; ++jj) {
        int j = (p & 1) * 2 + jj;
#pragma unroll
        for (int i = 0; i < 4; ++i) acc[i][j] = MFMA(af[i], bv[jj], acc[i][j]);
      }
      __builtin_amdgcn_s_setprio(0);
      SB();
      if (p < 3) BAR();
    }
    if (kt + 2 < 22) {
      asm volatile("s_waitcnt vmcnt(2)" ::: "memory");
    } else {
      asm volatile("s_waitcnt vmcnt(0)" ::: "memory");
    }
    SB();
    BAR();
  }

#pragma unroll
  for (int j = 0; j < 4; ++j) {
#pragma unroll
    for (int i = 0; i < 4; ++i) {
#pragma unroll
      for (int r = 0; r < 4; ++r) {
        int rl = wr + i * 16 + l4 * 4 + r;
        if (rl < valid)
          Out[(size_t)(row0 + rl) * DM + n0t * 128 + wcn + j * 16 + l15] =
              acc[i][j][r];
      }
    }
  }
}

extern "C" void kernel_launch(void* const* d_in, const int* in_sizes, int n_in,
                              void* d_out, int out_size, void* d_ws, size_t ws_size,
                              hipStream_t stream) {
  const float* inp = (const float*)d_in[0];
  const float* w_gate = (const float*)d_in[1];
  const float* w_up = (const float*)d_in[2];
  const float* w_down = (const float*)d_in[3];
  const int* cnt = (const int*)d_in[4];
  float* out = (float*)d_out;

  const size_t XI_ELEMS = (size_t)NTOK * DM;       // 128 MiB as bf16
  const size_t WELEMS = (size_t)E_NUM * DM * DH;   // 88 MiB as bf16
  if (ws_size < (XI_ELEMS + 3 * WELEMS) * sizeof(u16)) return;

  u16* Xi = (u16*)d_ws;        // X images [256][32][8192]
  u16* wgT = Xi + XI_ELEMS;    // gate tiles [E][11][32][8192]; later w_down
  u16* wuT = wgT + WELEMS;     // up tiles
  u16* Ht = wuT + WELEMS;      // H images [256][22][8192]

  xtile<<<dim3(32, 256), 256, 0, stream>>>(inp, Xi);
  wtile<<<dim3(DM / 64, DH / 128, E_NUM), 256, 0, stream>>>(w_gate, wgT, DM, DH);
  wtile<<<dim3(DM / 64, DH / 128, E_NUM), 256, 0, stream>>>(w_up, wuT, DM, DH);
  gemm_gate_up<<<dim3(TMAX, DH / 128), 512, 0, stream>>>(Xi, wgT, wuT, cnt, Ht);
  // wgT region dead now; reuse for w_down tiles [E][16][22][8192]
  wtile<<<dim3(DH / 64, DM / 128, E_NUM), 256, 0, stream>>>(w_down, wgT, DH, DM);
  gemm_down<<<dim3(TMAX, DM / 128), 512, 0, stream>>>(Ht, wgT, cnt, out);
}

// Round 6
// 1062.094 us; speedup vs baseline: 1.1031x; 1.0026x over previous
//
#include <hip/hip_runtime.h>

#define E_NUM 16
#define DM 2048
#define DH 1408
#define NTOK 32768
#define TMAX 144           // sum_e ceil(c_e/256) <= 128 + 16; 144 = 8*18
#define TILE_U16 8192      // one 128x64 bf16 image
#define XI_RS (32 * TILE_U16)   // u16 per 128-row X image group (32 ktiles)
#define HT_RS (22 * TILE_U16)   // u16 per 128-row H image group (22 ktiles)

typedef unsigned short u16;
typedef unsigned int u32;
typedef float f32x4 __attribute__((ext_vector_type(4)));
typedef __bf16 bf16x8 __attribute__((ext_vector_type(8)));
typedef short short8 __attribute__((ext_vector_type(8)));

__device__ __forceinline__ u16 f2bf(float x) {
  u32 u = __builtin_bit_cast(u32, x);
  u = (u + 0x7FFFu + ((u >> 16) & 1u)) >> 16;   // RNE
  return (u16)u;
}
__device__ __forceinline__ u32 f2bf2(float lo, float hi) {
  return (u32)f2bf(lo) | ((u32)f2bf(hi) << 16);
}

template <typename V>
__device__ __forceinline__ auto mfma_16x16x32(V a, V b, f32x4 c, int)
    -> decltype(__builtin_amdgcn_mfma_f32_16x16x32_bf16(a, b, c, 0, 0, 0)) {
  return __builtin_amdgcn_mfma_f32_16x16x32_bf16(a, b, c, 0, 0, 0);
}
template <typename V>
__device__ __forceinline__ f32x4 mfma_16x16x32(V a, V b, f32x4 c, long) {
  return __builtin_amdgcn_mfma_f32_16x16x32_bf16(
      __builtin_bit_cast(short8, a), __builtin_bit_cast(short8, b), c, 0, 0, 0);
}
__device__ __forceinline__ f32x4 MFMA(bf16x8 a, bf16x8 b, f32x4 c) {
  return mfma_16x16x32(a, b, c, 0);
}

__device__ __forceinline__ void gll16(const void* g, void* l) {
  __builtin_amdgcn_global_load_lds((const u32*)g, (u32*)l, 16, 0, 0);
}
__device__ __forceinline__ bf16x8 ld_frag(const u16* p) {
  return __builtin_bit_cast(bf16x8, *(const uint4*)p);
}
#define BAR() __builtin_amdgcn_s_barrier()

// ---------------------------------------------------------------------------
// X tiler: f32 [NTOK][DM] -> bf16 images [256][32][8192], phys chunk = c^(row&7)
// ---------------------------------------------------------------------------
__global__ void xtile(const float* __restrict__ src, u16* __restrict__ dst) {
  const int kt = blockIdx.x;   // 0..31
  const int rt = blockIdx.y;   // 0..255
  const int tid = threadIdx.x;
  const float* s = src + (size_t)rt * 128 * DM + kt * 64;
  u16* d = dst + (size_t)rt * XI_RS + (size_t)kt * TILE_U16;
#pragma unroll
  for (int i = 0; i < 4; ++i) {
    int u = i * 256 + tid;
    int row = u >> 3, c = u & 7;
    const float* p = s + (size_t)row * DM + c * 8;
    float4 v0 = *(const float4*)p, v1 = *(const float4*)(p + 4);
    uint4 w;
    w.x = f2bf2(v0.x, v0.y); w.y = f2bf2(v0.z, v0.w);
    w.z = f2bf2(v1.x, v1.y); w.w = f2bf2(v1.z, v1.w);
    *(uint4*)&d[(size_t)row * 64 + ((c ^ (row & 7)) * 8)] = w;
  }
}

// ---------------------------------------------------------------------------
// Weight tiler: f32 [E][K][N] -> bf16 images [E][N/128][K/64][8192]
// ---------------------------------------------------------------------------
__global__ void wtile(const float* __restrict__ src, u16* __restrict__ dst,
                      int K, int N) {
  __shared__ float t[64][133];
  __shared__ u16 img[TILE_U16];
  const int kt = blockIdx.x, nt = blockIdx.y, e = blockIdx.z;
  const int tid = threadIdx.x;
  const size_t sbase = (size_t)e * K * N + (size_t)kt * 64 * N + (size_t)nt * 128;

#pragma unroll
  for (int i = 0; i < 8; i++) {
    int uid = i * 256 + tid;
    int kr = uid >> 5, nc = (uid & 31) * 4;
    float4 v = *(const float4*)&src[sbase + (size_t)kr * N + nc];
    t[kr][nc + 0] = v.x; t[kr][nc + 1] = v.y;
    t[kr][nc + 2] = v.z; t[kr][nc + 3] = v.w;
  }
  __syncthreads();
#pragma unroll
  for (int i = 0; i < 4; i++) {
    int uid = i * 256 + tid;
    int row = uid >> 3, c = uid & 7;
    int kc = (c ^ (row & 7)) * 8;
    uint4 w;
    w.x = f2bf2(t[kc + 0][row], t[kc + 1][row]);
    w.y = f2bf2(t[kc + 2][row], t[kc + 3][row]);
    w.z = f2bf2(t[kc + 4][row], t[kc + 5][row]);
    w.w = f2bf2(t[kc + 6][row], t[kc + 7][row]);
    *(uint4*)&img[uid * 8] = w;
  }
  __syncthreads();
  const size_t dbase = (((size_t)e * (N / 128) + nt) * (K / 64) + kt) * TILE_U16;
#pragma unroll
  for (int i = 0; i < 4; i++) {
    int uid = i * 256 + tid;
    *(uint4*)&dst[dbase + uid * 8] = *(const uint4*)&img[uid * 8];
  }
}

// Map linear 256-row tile index -> (expert, row0, valid).
__device__ __forceinline__ bool tile_map(const int* __restrict__ cnt, int t,
                                         int& e_out, int& row0, int& valid) {
  int e = -1, ti = 0, seg0 = 0, segc = 0, tacc = 0, off = 0;
#pragma unroll
  for (int i = 0; i < E_NUM; i++) {
    int ci = cnt[i];
    int nt = (ci + 255) >> 8;
    if (e < 0 && t < tacc + nt) { e = i; ti = t - tacc; seg0 = off; segc = ci; }
    tacc += nt; off += ci;
  }
  if (e < 0) return false;
  e_out = e;
  row0 = seg0 + ti * 256;
  int v = seg0 + segc - row0;
  valid = v < 256 ? v : 256;
  return true;
}

__device__ __forceinline__ int xcd_swz(int bx) {
  return (bx & 7) * (TMAX / 8) + (bx >> 3);
}

// ---------------------------------------------------------------------------
// Fused gate+up grouped GEMM + SwiGLU. BM=256, BN=128, 512 thr, 8 waves.
// 4 phases/K-tile {reads; stage; [vmcnt@p3]; BAR; prio MFMA prio; BAR}.
// A 2-deep (stage kt+1 @p0), B 3-ring (stage kt+2 @p1); steady wait vmcnt(4)
// leaves B(kt+2)'s 4 loads in flight across the tile barrier.
// ---------------------------------------------------------------------------
__global__ __launch_bounds__(512, 2) void gemm_gate_up(
    const u16* __restrict__ Xi, const u16* __restrict__ WgT,
    const u16* __restrict__ WuT, const int* __restrict__ cnt,
    u16* __restrict__ H) {
  __shared__ u16 As[2][2 * TILE_U16];   // 64 KiB
  __shared__ u16 Bgs[3][TILE_U16];      // 48 KiB
  __shared__ u16 Bus[3][TILE_U16];      // 48 KiB

  int e, row0, valid;
  if (!tile_map(cnt, xcd_swz(blockIdx.x), e, row0, valid)) return;
  const int n0t = blockIdx.y;  // 0..10

  const int tid = threadIdx.x;
  const int lane = tid & 63;
  const int wave = tid >> 6;
  const int wr = (wave >> 1) * 64, wcn = (wave & 1) * 64;
  const int l15 = lane & 15, l4 = lane >> 4;
  const int swz = l15 & 7;

  const u16* pA[4];
#pragma unroll
  for (int q = 0; q < 4; ++q) {
    int u = q * 512 + tid;
    int lr = u >> 3, cs = u & 7;
    int R = row0 + (lr < valid ? lr : 0);
    int srcc = cs ^ (lr & 7) ^ (R & 7);
    pA[q] = Xi + (size_t)(R >> 7) * XI_RS + (size_t)(R & 127) * 64 + srcc * 8;
  }
  const size_t btb = (((size_t)e * 11 + n0t) * 32) * TILE_U16;
  const u16* pBg[2];
  const u16* pBu[2];
#pragma unroll
  for (int q = 0; q < 2; ++q) {
    pBg[q] = WgT + btb + (q * 512 + tid) * 8;
    pBu[q] = WuT + btb + (q * 512 + tid) * 8;
  }

  f32x4 accg[4][4], accu[4][4];
#pragma unroll
  for (int i = 0; i < 4; i++)
#pragma unroll
    for (int j = 0; j < 4; j++) {
      accg[i][j] = (f32x4){0.f, 0.f, 0.f, 0.f};
      accu[i][j] = (f32x4){0.f, 0.f, 0.f, 0.f};
    }

  // prologue: B(0), A(0), B(1); wait leaving B(1)'s 4 in flight
  asm volatile("s_waitcnt vmcnt(0)" ::: "memory");
#pragma unroll
  for (int q = 0; q < 2; ++q) {
    gll16(pBg[q], &Bgs[0][(q * 512 + tid) * 8]);
    gll16(pBu[q], &Bus[0][(q * 512 + tid) * 8]);
  }
#pragma unroll
  for (int q = 0; q < 4; ++q) gll16(pA[q], &As[0][(q * 512 + tid) * 8]);
#pragma unroll
  for (int q = 0; q < 2; ++q) {
    gll16(pBg[q] + TILE_U16, &Bgs[1][(q * 512 + tid) * 8]);
    gll16(pBu[q] + TILE_U16, &Bus[1][(q * 512 + tid) * 8]);
  }
  asm volatile("s_waitcnt vmcnt(4)" ::: "memory");
  BAR();

  int bs = 0;                 // B ring slot = kt % 3, rotated scalar-side
  for (int kt = 0; kt < 32; ++kt) {
    const u16* cA = &As[kt & 1][0];
    const u16* cBg = &Bgs[bs][0];
    const u16* cBu = &Bus[bs][0];
    bf16x8 af[4];

#pragma unroll
    for (int p = 0; p < 4; ++p) {
      const int kh = p >> 1;
      const int co = ((kh * 4 + l4) ^ swz) * 8;
      // --- phase reads ---
      if ((p & 1) == 0) {
#pragma unroll
        for (int i = 0; i < 4; ++i)
          af[i] = ld_frag(cA + (wr + i * 16 + l15) * 64 + co);
      }
      bf16x8 bgv[2], buv[2];
#pragma unroll
      for (int jj = 0; jj < 2; ++jj) {
        int j = (p & 1) * 2 + jj;
        bgv[jj] = ld_frag(cBg + (wcn + j * 16 + l15) * 64 + co);
        buv[jj] = ld_frag(cBu + (wcn + j * 16 + l15) * 64 + co);
      }
      // --- phase staging ---
      if (p == 0 && kt + 1 < 32) {
        const size_t ko = (size_t)(kt + 1) * TILE_U16;
        const int nb = (kt + 1) & 1;
#pragma unroll
        for (int q = 0; q < 4; ++q) gll16(pA[q] + ko, &As[nb][(q * 512 + tid) * 8]);
      }
      if (p == 1 && kt + 2 < 32) {
        const size_t ko = (size_t)(kt + 2) * TILE_U16;
        const int nb = bs == 0 ? 2 : bs - 1;   // (kt+2)%3
#pragma unroll
        for (int q = 0; q < 2; ++q) {
          gll16(pBg[q] + ko, &Bgs[nb][(q * 512 + tid) * 8]);
          gll16(pBu[q] + ko, &Bus[nb][(q * 512 + tid) * 8]);
        }
      }
      if (p == 3) {
        if (kt + 2 < 32) {
          asm volatile("s_waitcnt vmcnt(4)" ::: "memory");
        } else {
          asm volatile("s_waitcnt vmcnt(0)" ::: "memory");
        }
      }
      BAR();
      __builtin_amdgcn_s_setprio(1);
#pragma unroll
      for (int jj = 0; jj < 2; ++jj) {
        int j = (p & 1) * 2 + jj;
#pragma unroll
        for (int i = 0; i < 4; ++i) {
          accg[i][j] = MFMA(af[i], bgv[jj], accg[i][j]);
          accu[i][j] = MFMA(af[i], buv[jj], accu[i][j]);
        }
      }
      __builtin_amdgcn_s_setprio(0);
      BAR();
    }
    bs = bs == 2 ? 0 : bs + 1;
  }

  // epilogue: h = silu(gate)*up -> H swizzled images
#pragma unroll
  for (int j = 0; j < 4; ++j) {
    int col = n0t * 128 + wcn + j * 16 + l15;
    int kt_h = col >> 6, cc = (col & 63) >> 3, ce = col & 7;
#pragma unroll
    for (int i = 0; i < 4; ++i) {
      f32x4 g = accg[i][j], u = accu[i][j];
#pragma unroll
      for (int r = 0; r < 4; ++r) {
        int rl = wr + i * 16 + l4 * 4 + r;
        if (rl < valid) {
          int R = row0 + rl;
          float gv = g[r];
          float hv = gv / (1.f + __expf(-gv)) * u[r];
          size_t idx = (size_t)(R >> 7) * HT_RS + (size_t)kt_h * TILE_U16 +
                       (size_t)(R & 127) * 64 + ((cc ^ (R & 7)) * 8) + ce;
          H[idx] = f2bf(hv);
        }
      }
    }
  }
}

// ---------------------------------------------------------------------------
// Down grouped GEMM. Same 4-phase schedule; A 2-deep @p0, B 3-ring @p1,
// steady wait vmcnt(2). LDS = 112 KiB.
// ---------------------------------------------------------------------------
__global__ __launch_bounds__(512, 2) void gemm_down(
    const u16* __restrict__ Ht, const u16* __restrict__ WdT,
    const int* __restrict__ cnt, float* __restrict__ Out) {
  __shared__ u16 As[2][2 * TILE_U16];   // 64 KiB
  __shared__ u16 Bs[3][TILE_U16];       // 48 KiB

  int e, row0, valid;
  if (!tile_map(cnt, xcd_swz(blockIdx.x), e, row0, valid)) return;
  const int n0t = blockIdx.y;  // 0..15

  const int tid = threadIdx.x;
  const int lane = tid & 63;
  const int wave = tid >> 6;
  const int wr = (wave >> 1) * 64, wcn = (wave & 1) * 64;
  const int l15 = lane & 15, l4 = lane >> 4;
  const int swz = l15 & 7;

  const u16* pA[4];
#pragma unroll
  for (int q = 0; q < 4; ++q) {
    int u = q * 512 + tid;
    int lr = u >> 3, cs = u & 7;
    int R = row0 + (lr < valid ? lr : 0);
    int srcc = cs ^ (lr & 7) ^ (R & 7);
    pA[q] = Ht + (size_t)(R >> 7) * HT_RS + (size_t)(R & 127) * 64 + srcc * 8;
  }
  const size_t btb = (((size_t)e * 16 + n0t) * 22) * TILE_U16;
  const u16* pB[2];
#pragma unroll
  for (int q = 0; q < 2; ++q) pB[q] = WdT + btb + (q * 512 + tid) * 8;

  f32x4 acc[4][4];
#pragma unroll
  for (int i = 0; i < 4; i++)
#pragma unroll
    for (int j = 0; j < 4; j++) acc[i][j] = (f32x4){0.f, 0.f, 0.f, 0.f};

  asm volatile("s_waitcnt vmcnt(0)" ::: "memory");
#pragma unroll
  for (int q = 0; q < 2; ++q) gll16(pB[q], &Bs[0][(q * 512 + tid) * 8]);
#pragma unroll
  for (int q = 0; q < 4; ++q) gll16(pA[q], &As[0][(q * 512 + tid) * 8]);
#pragma unroll
  for (int q = 0; q < 2; ++q) gll16(pB[q] + TILE_U16, &Bs[1][(q * 512 + tid) * 8]);
  asm volatile("s_waitcnt vmcnt(2)" ::: "memory");
  BAR();

  int bs = 0;
  for (int kt = 0; kt < 22; ++kt) {
    const u16* cA = &As[kt & 1][0];
    const u16* cB = &Bs[bs][0];
    bf16x8 af[4];

#pragma unroll
    for (int p = 0; p < 4; ++p) {
      const int kh = p >> 1;
      const int co = ((kh * 4 + l4) ^ swz) * 8;
      if ((p & 1) == 0) {
#pragma unroll
        for (int i = 0; i < 4; ++i)
          af[i] = ld_frag(cA + (wr + i * 16 + l15) * 64 + co);
      }
      bf16x8 bv[2];
#pragma unroll
      for (int jj = 0; jj < 2; ++jj) {
        int j = (p & 1) * 2 + jj;
        bv[jj] = ld_frag(cB + (wcn + j * 16 + l15) * 64 + co);
      }
      if (p == 0 && kt + 1 < 22) {
        const size_t ko = (size_t)(kt + 1) * TILE_U16;
        const int nb = (kt + 1) & 1;
#pragma unroll
        for (int q = 0; q < 4; ++q) gll16(pA[q] + ko, &As[nb][(q * 512 + tid) * 8]);
      }
      if (p == 1 && kt + 2 < 22) {
        const size_t ko = (size_t)(kt + 2) * TILE_U16;
        const int nb = bs == 0 ? 2 : bs - 1;   // (kt+2)%3
#pragma unroll
        for (int q = 0; q < 2; ++q) gll16(pB[q] + ko, &Bs[nb][(q * 512 + tid) * 8]);
      }
      if (p == 3) {
        if (kt + 2 < 22) {
          asm volatile("s_waitcnt vmcnt(2)" ::: "memory");
        } else {
          asm volatile("s_waitcnt vmcnt(0)" ::: "memory");
        }
      }
      BAR();
      __builtin_amdgcn_s_setprio(1);
#pragma unroll
      for (int jj = 0; jj < 2; ++jj) {
        int j = (p & 1) * 2 + jj;
#pragma unroll
        for (int i = 0; i < 4; ++i) acc[i][j] = MFMA(af[i], bv[jj], acc[i][j]);
      }
      __builtin_amdgcn_s_setprio(0);
      BAR();
    }
    bs = bs == 2 ? 0 : bs + 1;
  }

#pragma unroll
  for (int j = 0; j < 4; ++j) {
#pragma unroll
    for (int i = 0; i < 4; ++i) {
#pragma unroll
      for (int r = 0; r < 4; ++r) {
        int rl = wr + i * 16 + l4 * 4 + r;
        if (rl < valid)
          Out[(size_t)(row0 + rl) * DM + n0t * 128 + wcn + j * 16 + l15] =
              acc[i][j][r];
      }
    }
  }
}

extern "C" void kernel_launch(void* const* d_in, const int* in_sizes, int n_in,
                              void* d_out, int out_size, void* d_ws, size_t ws_size,
                              hipStream_t stream) {
  const float* inp = (const float*)d_in[0];
  const float* w_gate = (const float*)d_in[1];
  const float* w_up = (const float*)d_in[2];
  const float* w_down = (const float*)d_in[3];
  const int* cnt = (const int*)d_in[4];
  float* out = (float*)d_out;

  const size_t XI_ELEMS = (size_t)NTOK * DM;       // 128 MiB as bf16
  const size_t WELEMS = (size_t)E_NUM * DM * DH;   // 88 MiB as bf16
  if (ws_size < (XI_ELEMS + 3 * WELEMS) * sizeof(u16)) return;

  u16* Xi = (u16*)d_ws;        // X images [256][32][8192]
  u16* wgT = Xi + XI_ELEMS;    // gate tiles [E][11][32][8192]; later w_down
  u16* wuT = wgT + WELEMS;     // up tiles
  u16* Ht = wuT + WELEMS;      // H images [256][22][8192]

  xtile<<<dim3(32, 256), 256, 0, stream>>>(inp, Xi);
  wtile<<<dim3(DM / 64, DH / 128, E_NUM), 256, 0, stream>>>(w_gate, wgT, DM, DH);
  wtile<<<dim3(DM / 64, DH / 128, E_NUM), 256, 0, stream>>>(w_up, wuT, DM, DH);
  gemm_gate_up<<<dim3(TMAX, DH / 128), 512, 0, stream>>>(Xi, wgT, wuT, cnt, Ht);
  // wgT region dead now; reuse for w_down tiles [E][16][22][8192]
  wtile<<<dim3(DH / 64, DM / 128, E_NUM), 256, 0, stream>>>(w_down, wgT, DH, DM);
  gemm_down<<<dim3(TMAX, DM / 128), 512, 0, stream>>>(Ht, wgT, cnt, out);
}